// Round 12
// baseline (125.672 us; speedup 1.0000x reference)
//
#include <hip/hip_runtime.h>
#include <hip/hip_cooperative_groups.h>
#include <hip/hip_bf16.h>

namespace cg = cooperative_groups;

typedef __attribute__((ext_vector_type(8))) short bf16x8;
typedef __attribute__((ext_vector_type(4))) float f32x4;

#define NB 1024
#define ND 256
#define MARGINF 0.3f
#define BIGV 1e9f
#define D2R 0.017453292519943295f
#define HD2R 0.008726646259971648f

// haversine 'a' thresholds: sin^2(T/(2*6371000)) (validated rounds 1-11)
#define A_POS 3.8495040e-12f   // 25 m
#define A_NEG 6.1592064e-11f   // 100 m

__device__ __forceinline__ float d4(float4 a, float4 b, float acc) {
    return fmaf(a.x,b.x, fmaf(a.y,b.y, fmaf(a.z,b.z, fmaf(a.w,b.w, acc))));
}

__device__ __forceinline__ void splitHL(float4 v0, float4 v1, bf16x8& H, bf16x8& L) {
    float f[8] = {v0.x, v0.y, v0.z, v0.w, v1.x, v1.y, v1.z, v1.w};
    #pragma unroll
    for (int q = 0; q < 8; ++q) {
        __hip_bfloat16 h = __float2bfloat16(f[q]);
        float hf = __bfloat162float(h);
        __hip_bfloat16 l = __float2bfloat16(f[q] - hf);
        H[q] = *(short*)&h;
        L[q] = *(short*)&l;
    }
}

// ---- shared device bodies (used by both fused and fallback kernels) ----

__device__ __forceinline__ void gram_body(
    const float* __restrict__ emb, const float* __restrict__ gps,
    float* __restrict__ sEnc, float* __restrict__ pP, int blk,
    float (&sSqI)[64], float (&sSqJ)[64], float4 (&sGI)[64], float4 (&sGJ)[64],
    float (&sRed)[64][33])
{
    const int tid = threadIdx.x, lane = tid & 63, w = tid >> 6;
    const int wr = w >> 1, wc = w & 1;
    const int ib = blk & 15, jb = blk >> 4;
    const int i0 = ib*64, j0 = jb*64;
    const int lr = lane & 15, lk = lane >> 4;
    const float4* __restrict__ emb4 = (const float4*)emb;

    // prologue: row norms (exact fp32) + gps scalars
    {
        const int half = tid & 1, r = (tid >> 1) & 63;
        const int base = (tid < 128) ? i0 : j0;
        const float4* rp = emb4 + (size_t)(base + r)*64 + half*32;
        float s = 0.f;
        #pragma unroll
        for (int q = 0; q < 32; ++q) s = d4(rp[q], rp[q], s);
        s += __shfl_xor(s, 1);
        if (half == 0) { if (tid < 128) sSqI[r] = s; else sSqJ[r] = s; }
    }
    if (tid < 128) {
        const int r = tid & 63;
        const int base = (tid < 64) ? i0 : j0;
        float2 g = ((const float2*)gps)[base + r];
        float4 gi = make_float4(g.x, g.y, cosf(g.x * D2R), 0.f);
        if (tid < 64) sGI[r] = gi; else sGJ[r] = gi;
    }
    __syncthreads();

    f32x4 acc[2][2] = {};
    #pragma unroll 2
    for (int k8 = 0; k8 < 8; ++k8) {
        const int co = k8*8 + lk*2;
        const float4* pa0 = emb4 + (size_t)(i0 + wr*32      + lr)*64 + co;
        const float4* pa1 = emb4 + (size_t)(i0 + wr*32 + 16 + lr)*64 + co;
        const float4* pb0 = emb4 + (size_t)(j0 + wc*32      + lr)*64 + co;
        const float4* pb1 = emb4 + (size_t)(j0 + wc*32 + 16 + lr)*64 + co;
        bf16x8 a0H,a0L,a1H,a1L,b0H,b0L,b1H,b1L;
        splitHL(pa0[0], pa0[1], a0H, a0L);
        splitHL(pa1[0], pa1[1], a1H, a1L);
        splitHL(pb0[0], pb0[1], b0H, b0L);
        splitHL(pb1[0], pb1[1], b1H, b1L);
        acc[0][0] = __builtin_amdgcn_mfma_f32_16x16x32_bf16(a0H, b0H, acc[0][0], 0,0,0);
        acc[0][1] = __builtin_amdgcn_mfma_f32_16x16x32_bf16(a0H, b1H, acc[0][1], 0,0,0);
        acc[1][0] = __builtin_amdgcn_mfma_f32_16x16x32_bf16(a1H, b0H, acc[1][0], 0,0,0);
        acc[1][1] = __builtin_amdgcn_mfma_f32_16x16x32_bf16(a1H, b1H, acc[1][1], 0,0,0);
        acc[0][0] = __builtin_amdgcn_mfma_f32_16x16x32_bf16(a0L, b0H, acc[0][0], 0,0,0);
        acc[0][1] = __builtin_amdgcn_mfma_f32_16x16x32_bf16(a0L, b1H, acc[0][1], 0,0,0);
        acc[1][0] = __builtin_amdgcn_mfma_f32_16x16x32_bf16(a1L, b0H, acc[1][0], 0,0,0);
        acc[1][1] = __builtin_amdgcn_mfma_f32_16x16x32_bf16(a1L, b1H, acc[1][1], 0,0,0);
        acc[0][0] = __builtin_amdgcn_mfma_f32_16x16x32_bf16(a0H, b0L, acc[0][0], 0,0,0);
        acc[0][1] = __builtin_amdgcn_mfma_f32_16x16x32_bf16(a0H, b1L, acc[0][1], 0,0,0);
        acc[1][0] = __builtin_amdgcn_mfma_f32_16x16x32_bf16(a1H, b0L, acc[1][0], 0,0,0);
        acc[1][1] = __builtin_amdgcn_mfma_f32_16x16x32_bf16(a1H, b1L, acc[1][1], 0,0,0);
    }

    float sqj[2]; float4 gj2[2];
    sqj[0] = sSqJ[wc*32 + lr];      gj2[0] = sGJ[wc*32 + lr];
    sqj[1] = sSqJ[wc*32 + 16 + lr]; gj2[1] = sGJ[wc*32 + 16 + lr];

    #pragma unroll
    for (int fi = 0; fi < 2; ++fi) {
        #pragma unroll
        for (int r = 0; r < 4; ++r) {
            const int rl = wr*32 + fi*16 + lk*4 + r;
            const int gi = i0 + rl;
            const float sqi = sSqI[rl];
            const float4 gvi = sGI[rl];
            float pmax = -1.f;
            #pragma unroll
            for (int fj = 0; fj < 2; ++fj) {
                const int gj = j0 + wc*32 + fj*16 + lr;
                float d2v = sqi + sqj[fj] - 2.f*acc[fi][fj][r];
                d2v = d2v > 0.f ? d2v : 0.f;
                const float sla = sinf((gj2[fj].x - gvi.x) * HD2R);
                const float slo = sinf((gj2[fj].y - gvi.y) * HD2R);
                const float hav = fmaf(sla, sla, (gvi.z * gj2[fj].z) * (slo*slo));
                const bool pos = (hav < A_POS) && (gi != gj);
                const bool neg = (hav > A_NEG);
                pmax = fmaxf(pmax, pos ? d2v : -1.f);
                sEnc[(size_t)gi*NB + gj] = neg ? d2v : BIGV;
            }
            sRed[rl][lr + 16*wc] = pmax;
        }
    }
    __syncthreads();
    if (tid < 64) {
        float m = sRed[tid][0];
        #pragma unroll
        for (int c = 1; c < 32; ++c) m = fmaxf(m, sRed[tid][c]);
        pP[(i0 + tid)*16 + jb] = m;
    }
}

__device__ __forceinline__ void rows_body(
    const float* __restrict__ sEnc, const float* __restrict__ pP,
    float* __restrict__ tri, float* __restrict__ val, int blk)
{
    const int tid = threadIdx.x, lane = tid & 63, w = tid >> 6;
    const int i = blk*4 + w;

    float p = pP[i*16 + (lane & 15)];
    #pragma unroll
    for (int off = 1; off < 16; off <<= 1) p = fmaxf(p, __shfl_xor(p, off));
    const float dap2 = p;
    const bool has_pos = dap2 > -0.5f;
    float lo2 = -1.f, hi2 = -1.f;
    if (has_pos) { const float hb = sqrtf(dap2) + MARGINF; lo2 = dap2; hi2 = hb*hb; }

    float nmin = BIGV, smin = BIGV;
    const float4* __restrict__ row = (const float4*)sEnc + (size_t)i*256;
    #pragma unroll
    for (int pss = 0; pss < 4; ++pss) {
        const float4 x = row[pss*64 + lane];
        #pragma unroll
        for (int q = 0; q < 4; ++q) {
            const float xc = (q==0) ? x.x : (q==1) ? x.y : (q==2) ? x.z : x.w;
            nmin = fminf(nmin, xc);
            smin = fminf(smin, (xc > lo2 && xc < hi2) ? xc : BIGV);
        }
    }
    #pragma unroll
    for (int off = 1; off < 64; off <<= 1) {
        nmin = fminf(nmin, __shfl_xor(nmin, off));
        smin = fminf(smin, __shfl_xor(smin, off));
    }
    if (lane == 0) {
        const bool has_neg  = nmin < 0.5f*BIGV;
        const bool has_semi = smin < 0.5f*BIGV;
        const float dan2 = has_semi ? smin : nmin;
        const float dap  = has_pos ? sqrtf(dap2) : 0.f;
        float t = dap - sqrtf(dan2) + MARGINF;
        t = t > 0.f ? t : 0.f;
        const bool valid = has_pos && has_neg;
        tri[i] = valid ? t : 0.f;
        val[i] = valid ? 1.f : 0.f;
    }
}

__device__ __forceinline__ void final_body(
    const float* __restrict__ tri, const float* __restrict__ val,
    float* __restrict__ out, float (&rt)[4], float (&rv)[4])
{
    const int tid = threadIdx.x;
    float st = 0.f, sv = 0.f;
    #pragma unroll
    for (int g = 0; g < 4; ++g) { st += tri[tid + (g<<8)]; sv += val[tid + (g<<8)]; }
    #pragma unroll
    for (int off = 1; off < 64; off <<= 1) { st += __shfl_xor(st, off); sv += __shfl_xor(sv, off); }
    if ((tid & 63) == 0) { rt[tid>>6] = st; rv[tid>>6] = sv; }
    __syncthreads();
    if (tid == 0) {
        float t = rt[0]+rt[1]+rt[2]+rt[3];
        float v = rv[0]+rv[1]+rv[2]+rv[3];
        out[0] = t / fmaxf(v, 1.f);
    }
}

// ---- fused cooperative kernel: gram -> grid.sync -> rows -> grid.sync -> final ----
__global__ __launch_bounds__(256) void fused_kernel(
    const float* __restrict__ emb, const float* __restrict__ gps,
    float* __restrict__ sEnc, float* __restrict__ pP,
    float* __restrict__ tri, float* __restrict__ val, float* __restrict__ out)
{
    __shared__ float  sSqI[64], sSqJ[64];
    __shared__ float4 sGI[64], sGJ[64];
    __shared__ float  sRed[64][33];
    __shared__ float  rt[4], rv[4];

    cg::grid_group grid = cg::this_grid();

    gram_body(emb, gps, sEnc, pP, blockIdx.x, sSqI, sSqJ, sGI, sGJ, sRed);
    __threadfence();            // device-scope release (XCD L2 non-coherence, G16)
    grid.sync();

    rows_body(sEnc, pP, tri, val, blockIdx.x);
    __threadfence();
    grid.sync();

    if (blockIdx.x == 0) final_body(tri, val, out, rt, rv);
}

// ---- fallback 3-kernel path (r11, proven) ----
__global__ __launch_bounds__(256) void gram_mfma(
    const float* __restrict__ emb, const float* __restrict__ gps,
    float* __restrict__ sEnc, float* __restrict__ pP)
{
    __shared__ float  sSqI[64], sSqJ[64];
    __shared__ float4 sGI[64], sGJ[64];
    __shared__ float  sRed[64][33];
    gram_body(emb, gps, sEnc, pP, blockIdx.x, sSqI, sSqJ, sGI, sGJ, sRed);
}
__global__ __launch_bounds__(256) void rows_kernel(
    const float* __restrict__ sEnc, const float* __restrict__ pP,
    float* __restrict__ tri, float* __restrict__ val)
{
    rows_body(sEnc, pP, tri, val, blockIdx.x);
}
__global__ __launch_bounds__(256) void finalize_kernel(
    const float* __restrict__ tri, const float* __restrict__ val, float* __restrict__ out)
{
    __shared__ float rt[4], rv[4];
    final_body(tri, val, out, rt, rv);
}

extern "C" void kernel_launch(void* const* d_in, const int* in_sizes, int n_in,
                              void* d_out, int out_size, void* d_ws, size_t ws_size,
                              hipStream_t stream) {
    const float* emb = (const float*)d_in[0];   // [1024,256] f32
    const float* gps = (const float*)d_in[1];   // [1024,2]  f32
    float* ws = (float*)d_ws;

    float* sEnc = ws;                    // 1024*1024 f32 = 4 MB
    float* pP   = ws + 1048576;          // 1024*16
    float* tri  = pP + 16384;            // 1024
    float* val  = tri + 1024;            // 1024
    float* outp = (float*)d_out;

    void* args[] = { (void*)&emb, (void*)&gps, (void*)&sEnc, (void*)&pP,
                     (void*)&tri, (void*)&val, (void*)&outp };
    hipError_t e = hipLaunchCooperativeKernel(
        reinterpret_cast<void*>(fused_kernel), dim3(256), dim3(256), args, 0, stream);
    if (e != hipSuccess) {
        gram_mfma<<<256, 256, 0, stream>>>(emb, gps, sEnc, pP);
        rows_kernel<<<256, 256, 0, stream>>>(sEnc, pP, tri, val);
        finalize_kernel<<<1, 256, 0, stream>>>(tri, val, outp);
    }
}

// Round 13
// 37.680 us; speedup vs baseline: 3.3353x; 3.3353x over previous
//
#include <hip/hip_runtime.h>
#include <hip/hip_bf16.h>

typedef __attribute__((ext_vector_type(8))) short bf16x8;
typedef __attribute__((ext_vector_type(4))) float f32x4;

#define NB 1024
#define ND 256
#define MARGINF 0.3f
#define BIGV 1e9f
#define D2R 0.017453292519943295f
#define HD2R 0.008726646259971648f

// haversine 'a' thresholds: sin^2(T/(2*6371000)) (validated rounds 1-12)
#define A_POS 3.8495040e-12f   // 25 m
#define A_NEG 6.1592064e-11f   // 100 m

__device__ __forceinline__ float d4(float4 a, float4 b, float acc) {
    return fmaf(a.x,b.x, fmaf(a.y,b.y, fmaf(a.z,b.z, fmaf(a.w,b.w, acc))));
}

__device__ __forceinline__ void splitHL(float4 v0, float4 v1, bf16x8& H, bf16x8& L) {
    float f[8] = {v0.x, v0.y, v0.z, v0.w, v1.x, v1.y, v1.z, v1.w};
    #pragma unroll
    for (int q = 0; q < 8; ++q) {
        __hip_bfloat16 h = __float2bfloat16(f[q]);
        float hf = __bfloat162float(h);
        __hip_bfloat16 l = __float2bfloat16(f[q] - hf);
        H[q] = *(short*)&h;
        L[q] = *(short*)&l;
    }
}

// K1: MFMA Gram, 64x64 tile, 512 thr / 8 waves (2 waves/SIMD). Wave = 32x16 out.
// G = HH' + LH' + HL'; d^2 = sq_i + sq_j - 2G (exact fp32 norms).
// Also zeroes the cross-kernel reduction cells (block 0) for the 2nd kernel.
__global__ __launch_bounds__(512) void gram_mfma(
    const float* __restrict__ emb, const float* __restrict__ gps,
    float* __restrict__ sEnc, float* __restrict__ pP, float* __restrict__ flags)
{
    __shared__ float  sSqI[64], sSqJ[64];
    __shared__ float4 sGI[64], sGJ[64];
    __shared__ float  sRed[64][65];

    const int tid = threadIdx.x, lane = tid & 63, w = tid >> 6;
    const int wr = w >> 2, wc = w & 3;              // 2x4 wave grid
    const int ib = blockIdx.x & 15, jb = blockIdx.x >> 4;
    const int i0 = ib*64, j0 = jb*64;
    const int lr = lane & 15, lk = lane >> 4;
    const float4* __restrict__ emb4 = (const float4*)emb;

    if (blockIdx.x == 0 && tid < 3) flags[tid] = 0.f;   // gsum, gcnt, done

    // prologue: row norms (quarter-rows, all 512 thr) + gps scalars
    {
        const int q4 = tid & 3, r = (tid >> 2) & 63;
        const int base = (tid < 256) ? i0 : j0;
        const float4* rp = emb4 + (size_t)(base + r)*64 + q4*16;
        float s = 0.f;
        #pragma unroll
        for (int q = 0; q < 16; ++q) s = d4(rp[q], rp[q], s);
        s += __shfl_xor(s, 1);
        s += __shfl_xor(s, 2);
        if (q4 == 0) { if (tid < 256) sSqI[r] = s; else sSqJ[r] = s; }
    }
    if (tid < 128) {
        const int r = tid & 63;
        const int base = (tid < 64) ? i0 : j0;
        float2 g = ((const float2*)gps)[base + r];
        float4 gi = make_float4(g.x, g.y, cosf(g.x * D2R), 0.f);
        if (tid < 64) sGI[r] = gi; else sGJ[r] = gi;
    }
    __syncthreads();

    // MFMA loop: 8 k-windows x {6 loads -> 3 splits -> 6 MFMAs}
    f32x4 acc0 = {}, acc1 = {};
    #pragma unroll 2
    for (int k8 = 0; k8 < 8; ++k8) {
        const int co = k8*8 + lk*2;
        const float4* pa0 = emb4 + (size_t)(i0 + wr*32      + lr)*64 + co;
        const float4* pa1 = emb4 + (size_t)(i0 + wr*32 + 16 + lr)*64 + co;
        const float4* pb0 = emb4 + (size_t)(j0 + wc*16      + lr)*64 + co;
        bf16x8 a0H,a0L,a1H,a1L,b0H,b0L;
        splitHL(pa0[0], pa0[1], a0H, a0L);
        splitHL(pa1[0], pa1[1], a1H, a1L);
        splitHL(pb0[0], pb0[1], b0H, b0L);
        acc0 = __builtin_amdgcn_mfma_f32_16x16x32_bf16(a0H, b0H, acc0, 0,0,0);
        acc1 = __builtin_amdgcn_mfma_f32_16x16x32_bf16(a1H, b0H, acc1, 0,0,0);
        acc0 = __builtin_amdgcn_mfma_f32_16x16x32_bf16(a0L, b0H, acc0, 0,0,0);
        acc1 = __builtin_amdgcn_mfma_f32_16x16x32_bf16(a1L, b0H, acc1, 0,0,0);
        acc0 = __builtin_amdgcn_mfma_f32_16x16x32_bf16(a0H, b0L, acc0, 0,0,0);
        acc1 = __builtin_amdgcn_mfma_f32_16x16x32_bf16(a1H, b0L, acc1, 0,0,0);
    }

    // epilogue: d^2, masks, sEnc encode, per-row pmax partials
    const float  sqj = sSqJ[wc*16 + lr];
    const float4 gj2 = sGJ[wc*16 + lr];
    const int    gj  = j0 + wc*16 + lr;

    #pragma unroll
    for (int fi = 0; fi < 2; ++fi) {
        const f32x4 a = fi ? acc1 : acc0;
        #pragma unroll
        for (int r = 0; r < 4; ++r) {
            const int rl = wr*32 + fi*16 + lk*4 + r;
            const int gi = i0 + rl;
            float d2v = sSqI[rl] + sqj - 2.f*a[r];
            d2v = d2v > 0.f ? d2v : 0.f;
            const float4 gvi = sGI[rl];
            const float sla = sinf((gj2.x - gvi.x) * HD2R);
            const float slo = sinf((gj2.y - gvi.y) * HD2R);
            const float hav = fmaf(sla, sla, (gvi.z * gj2.z) * (slo*slo));
            const bool pos = (hav < A_POS) && (gi != gj);
            const bool neg = (hav > A_NEG);
            sEnc[(size_t)gi*NB + gj] = neg ? d2v : BIGV;
            sRed[rl][wc*16 + lr] = pos ? d2v : -1.f;
        }
    }
    __syncthreads();
    // note: sRed[rl][c] holds the POS-masked d2 for a single (row, col) pair
    // (one writer each); per-row max over 64 cols below.
    if (tid < 64) {
        float m = sRed[tid][0];
        #pragma unroll
        for (int c = 1; c < 64; ++c) m = fmaxf(m, sRed[tid][c]);
        pP[(i0 + tid)*16 + jb] = m;
    }
}

// K2: per-row finalize + last-block loss emit (no 3rd kernel).
__global__ __launch_bounds__(256) void rows_final(
    const float* __restrict__ sEnc, const float* __restrict__ pP,
    float* __restrict__ flags, float* __restrict__ out)
{
    __shared__ float sT[4], sV[4];
    const int tid = threadIdx.x, lane = tid & 63, w = tid >> 6;
    const int i = blockIdx.x*4 + w;

    float p = pP[i*16 + (lane & 15)];
    #pragma unroll
    for (int off = 1; off < 16; off <<= 1) p = fmaxf(p, __shfl_xor(p, off));
    const float dap2 = p;
    const bool has_pos = dap2 > -0.5f;
    float lo2 = -1.f, hi2 = -1.f;
    if (has_pos) { const float hb = sqrtf(dap2) + MARGINF; lo2 = dap2; hi2 = hb*hb; }

    float nmin = BIGV, smin = BIGV;
    const float4* __restrict__ row = (const float4*)sEnc + (size_t)i*256;
    #pragma unroll
    for (int pss = 0; pss < 4; ++pss) {
        const float4 x = row[pss*64 + lane];
        #pragma unroll
        for (int q = 0; q < 4; ++q) {
            const float xc = (q==0) ? x.x : (q==1) ? x.y : (q==2) ? x.z : x.w;
            nmin = fminf(nmin, xc);
            smin = fminf(smin, (xc > lo2 && xc < hi2) ? xc : BIGV);
        }
    }
    #pragma unroll
    for (int off = 1; off < 64; off <<= 1) {
        nmin = fminf(nmin, __shfl_xor(nmin, off));
        smin = fminf(smin, __shfl_xor(smin, off));
    }
    if (lane == 0) {
        const bool has_neg  = nmin < 0.5f*BIGV;
        const bool has_semi = smin < 0.5f*BIGV;
        const float dan2 = has_semi ? smin : nmin;
        const float dap  = has_pos ? sqrtf(dap2) : 0.f;
        float t = dap - sqrtf(dan2) + MARGINF;
        t = t > 0.f ? t : 0.f;
        const bool valid = has_pos && has_neg;
        sT[w] = valid ? t : 0.f;
        sV[w] = valid ? 1.f : 0.f;
    }
    __syncthreads();
    if (tid == 0) {
        const float st = sT[0]+sT[1]+sT[2]+sT[3];
        const float sv = sV[0]+sV[1]+sV[2]+sV[3];
        atomicAdd(&flags[0], st);
        atomicAdd(&flags[1], sv);
        __threadfence();
        const unsigned old = atomicAdd((unsigned*)&flags[2], 1u);
        if (old == 255u) {             // last block to finish (order-independent)
            const float t = atomicAdd(&flags[0], 0.f);
            const float v = atomicAdd(&flags[1], 0.f);
            out[0] = t / fmaxf(v, 1.f);
        }
    }
}

extern "C" void kernel_launch(void* const* d_in, const int* in_sizes, int n_in,
                              void* d_out, int out_size, void* d_ws, size_t ws_size,
                              hipStream_t stream) {
    const float* emb = (const float*)d_in[0];   // [1024,256] f32
    const float* gps = (const float*)d_in[1];   // [1024,2]  f32
    float* ws = (float*)d_ws;

    float* sEnc  = ws;                    // 1024*1024 f32 = 4 MB
    float* pP    = ws + 1048576;          // 1024*16
    float* flags = pP + 16384;            // {gsum, gcnt, done}

    gram_mfma<<<256, 512, 0, stream>>>(emb, gps, sEnc, pP, flags);
    rows_final<<<256, 256, 0, stream>>>(sEnc, pP, flags, (float*)d_out);
}